// Round 7
// baseline (767.224 us; speedup 1.0000x reference)
//
#include <hip/hip_runtime.h>
#include <cstdint>
#include <cstddef>

typedef short short8 __attribute__((ext_vector_type(8)));
typedef float f32x4 __attribute__((ext_vector_type(4)));
typedef unsigned short ushort_t;

#define D_MODEL 1024
#define D_FF    2816
#define SEQ     2048
#define BATCH   2
#define NHEADS  16
#define DK      64
#define NTOK    (BATCH*SEQ)   // 4096

__device__ __forceinline__ float bf2f(ushort_t u) {
  return __builtin_bit_cast(float, (unsigned int)u << 16);
}
__device__ __forceinline__ ushort_t f2bf(float f) {
  unsigned int x = __builtin_bit_cast(unsigned int, f);
  x += 0x7fffu + ((x >> 16) & 1u);   // round-to-nearest-even
  return (ushort_t)(x >> 16);
}

// async global->LDS, 16B per lane. LDS dest = wave-uniform base + lane*16.
__device__ __forceinline__ void gld16(const ushort_t* g, ushort_t* l) {
  __builtin_amdgcn_global_load_lds(
      (const __attribute__((address_space(1))) unsigned int*)g,
      (__attribute__((address_space(3))) unsigned int*)l,
      16, 0, 0);
}

// ---------------- fp32 -> bf16 convert, all 7 weights in one launch ----------------
// mul/ofs remap rows for the W1/W3 interleave: dst row = src_row*mul + ofs.
// All weights have K=1024 -> 256 float4 per row.
struct CvtArgs {
  const float* src[7];
  ushort_t* dst[7];
  int nblk[7];
  int mul[7];
  int ofs[7];
};
__global__ __launch_bounds__(256) void convert_all(CvtArgs a) {
  int off = blockIdx.x;
  int seg = 0;
  while (off >= a.nblk[seg]) { off -= a.nblk[seg]; seg++; }   // wave-uniform
  int i = off * 256 + threadIdx.x;
  int row = i >> 8, c = i & 255;
  float4 v = ((const float4*)a.src[seg])[i];
  ushort4 o;
  o.x = f2bf(v.x); o.y = f2bf(v.y); o.z = f2bf(v.z); o.w = f2bf(v.w);
  ((ushort4*)a.dst[seg])[(size_t)(row * a.mul[seg] + a.ofs[seg]) * 256 + c] = o;
}

// ---------------- RMSNorm (row of 1024) ----------------
__global__ __launch_bounds__(256) void rmsnorm_kernel(
    const float* __restrict__ x, const float* __restrict__ g, ushort_t* __restrict__ out) {
  int row = blockIdx.x;
  int tid = threadIdx.x;
  float4 v = ((const float4*)(x + (size_t)row * D_MODEL))[tid];
  float ss = v.x*v.x + v.y*v.y + v.z*v.z + v.w*v.w;
#pragma unroll
  for (int off = 1; off < 64; off <<= 1) ss += __shfl_xor(ss, off);
  __shared__ float wsum[4];
  if ((tid & 63) == 0) wsum[tid >> 6] = ss;
  __syncthreads();
  float total = wsum[0] + wsum[1] + wsum[2] + wsum[3];
  float rinv = rsqrtf(total * (1.0f / D_MODEL) + 1e-5f);
  float4 gv = ((const float4*)g)[tid];
  ushort4 o;
  o.x = f2bf(v.x * gv.x * rinv);
  o.y = f2bf(v.y * gv.y * rinv);
  o.z = f2bf(v.z * gv.z * rinv);
  o.w = f2bf(v.w * gv.w * rinv);
  ((ushort4*)(out + (size_t)row * D_MODEL))[tid] = o;
}

// ---- y = sum(4 partials) + x; h = rmsnorm(y)*g  (fused WO split-K reduce) ----
__global__ __launch_bounds__(256) void rmsnorm_reduce4(
    const float* __restrict__ part, const float* __restrict__ x,
    const float* __restrict__ g, float* __restrict__ y, ushort_t* __restrict__ h) {
  const int row = blockIdx.x;
  const int tid = threadIdx.x;
  const size_t i = (size_t)row * 256 + tid;           // float4 index
  const size_t MN4 = (size_t)NTOK * (D_MODEL / 4);
  float4 v = ((const float4*)x)[i];
#pragma unroll
  for (int jp = 0; jp < 4; jp++) {
    float4 pv = ((const float4*)part)[jp * MN4 + i];
    v.x += pv.x; v.y += pv.y; v.z += pv.z; v.w += pv.w;
  }
  ((float4*)y)[i] = v;
  float ss = v.x*v.x + v.y*v.y + v.z*v.z + v.w*v.w;
#pragma unroll
  for (int off = 1; off < 64; off <<= 1) ss += __shfl_xor(ss, off);
  __shared__ float wsum[4];
  if ((tid & 63) == 0) wsum[tid >> 6] = ss;
  __syncthreads();
  float total = wsum[0] + wsum[1] + wsum[2] + wsum[3];
  float rinv = rsqrtf(total * (1.0f / D_MODEL) + 1e-5f);
  float4 gv = ((const float4*)g)[tid];
  ushort4 o;
  o.x = f2bf(v.x * gv.x * rinv);
  o.y = f2bf(v.y * gv.y * rinv);
  o.z = f2bf(v.z * gv.z * rinv);
  o.w = f2bf(v.w * gv.w * rinv);
  ((ushort4*)(h + (size_t)row * D_MODEL))[tid] = o;
}

// ---- out = sum(4 partials) + y  (W2 split-K reduce + final residual) ----
__global__ __launch_bounds__(256) void add_reduce4(
    const float* __restrict__ part, const float* __restrict__ y, float* __restrict__ out) {
  const size_t i = (size_t)blockIdx.x * 256 + threadIdx.x;
  const size_t MN4 = (size_t)NTOK * (D_MODEL / 4);
  float4 v = ((const float4*)y)[i];
#pragma unroll
  for (int jp = 0; jp < 4; jp++) {
    float4 pv = ((const float4*)part)[jp * MN4 + i];
    v.x += pv.x; v.y += pv.y; v.z += pv.z; v.w += pv.w;
  }
  ((float4*)out)[i] = v;
}

// ======== shared K-loop macro body (m97 structure): fills acc[4][4] ========
#define GEMM_KLOOP(Aptr, Bptr, KBEG, KEND, KSTRIDE)                              \
  const int tid  = threadIdx.x;                                                  \
  const int w    = tid >> 6;                                                     \
  const int lane = tid & 63;                                                     \
  const int col  = lane & 15;                                                    \
  const int quad = lane >> 4;                                                    \
  const int waveM = (w >> 1) * 64;                                               \
  const int waveN = (w & 1) * 64;                                                \
  const int bm = blockIdx.y * 128;                                               \
  const int bn = blockIdx.x * 128;                                               \
  f32x4 acc[4][4] = {};                                                          \
  {                                                                              \
    const int srow = tid >> 2;                                                   \
    const int scol = (tid & 3) * 8;                                              \
    const ushort_t* gA = (Aptr) + (size_t)(bm + srow) * (KSTRIDE) + scol;        \
    const ushort_t* gB = (Bptr) + (size_t)(bn + srow) * (KSTRIDE) + scol;        \
    ushort_t* lA = sA + tid * 8;                                                 \
    ushort_t* lB = sB + tid * 8;                                                 \
    const size_t rstep = (size_t)64 * (KSTRIDE);                                 \
    for (int k0 = (KBEG); k0 < (KEND); k0 += 32) {                               \
      gld16(gA + k0,         lA);                                                \
      gld16(gA + k0 + rstep, lA + 2048);                                         \
      gld16(gB + k0,         lB);                                                \
      gld16(gB + k0 + rstep, lB + 2048);                                         \
      __syncthreads();                                                           \
      short8 af[4], bfm[4];                                                      \
      _Pragma("unroll")                                                          \
      for (int mi = 0; mi < 4; mi++)                                             \
        af[mi] = *(const short8*)&sA[(waveM + mi * 16 + col) * 32 + quad * 8];   \
      _Pragma("unroll")                                                          \
      for (int ni = 0; ni < 4; ni++)                                             \
        bfm[ni] = *(const short8*)&sB[(waveN + ni * 16 + col) * 32 + quad * 8];  \
      _Pragma("unroll")                                                          \
      for (int mi = 0; mi < 4; mi++)                                             \
        _Pragma("unroll")                                                        \
        for (int ni = 0; ni < 4; ni++)                                           \
          acc[mi][ni] = __builtin_amdgcn_mfma_f32_16x16x32_bf16(af[mi], bfm[ni], acc[mi][ni], 0, 0, 0); \
      __syncthreads();                                                           \
    }                                                                            \
  }

// ---------------- generic GEMM (EPI 0: bf16 store; 1: fp32 + resid) ----------------
struct GemmArgs {
  const ushort_t* A;
  const ushort_t* B0; const ushort_t* B1; const ushort_t* B2;
  void* C0; void* C1; void* C2;
  const float* resid;
  int M, N, K;
};

template<int EPI>
__global__ __launch_bounds__(256) void gemm128(GemmArgs args) {
  const ushort_t* B = blockIdx.z == 0 ? args.B0 : (blockIdx.z == 1 ? args.B1 : args.B2);
  void* C = blockIdx.z == 0 ? args.C0 : (blockIdx.z == 1 ? args.C1 : args.C2);
  const int N = args.N, K = args.K;
  __shared__ __align__(16) ushort_t sA[128 * 32];
  __shared__ __align__(16) ushort_t sB[128 * 32];
  GEMM_KLOOP(args.A, B, 0, K, K)
#pragma unroll
  for (int mi = 0; mi < 4; mi++) {
    int r0 = bm + waveM + mi * 16 + quad * 4;
#pragma unroll
    for (int ni = 0; ni < 4; ni++) {
      int c0 = bn + waveN + ni * 16 + col;
#pragma unroll
      for (int r = 0; r < 4; r++) {
        size_t idx = (size_t)(r0 + r) * N + c0;
        if (EPI == 0) ((ushort_t*)C)[idx] = f2bf(acc[mi][ni][r]);
        else          ((float*)C)[idx]    = acc[mi][ni][r] + args.resid[idx];
      }
    }
  }
}

// ---- split-K variant: grid.z = 4 K-chunks, fp32 partials to C[z][M*N] ----
struct GemmSplitArgs {
  const ushort_t* A; const ushort_t* B;
  float* C;
  int N, K, kchunk;
};

__global__ __launch_bounds__(256) void gemm128_splitk(GemmSplitArgs args) {
  const int N = args.N, K = args.K;
  const int kbeg = blockIdx.z * args.kchunk;
  const int kend = kbeg + args.kchunk;
  __shared__ __align__(16) ushort_t sA[128 * 32];
  __shared__ __align__(16) ushort_t sB[128 * 32];
  GEMM_KLOOP(args.A, args.B, kbeg, kend, K)
  float* C = args.C + (size_t)blockIdx.z * ((size_t)NTOK * N);
#pragma unroll
  for (int mi = 0; mi < 4; mi++) {
    int r0 = bm + waveM + mi * 16 + quad * 4;
#pragma unroll
    for (int ni = 0; ni < 4; ni++) {
      int c0 = bn + waveN + ni * 16 + col;
#pragma unroll
      for (int r = 0; r < 4; r++)
        C[(size_t)(r0 + r) * N + c0] = acc[mi][ni][r];
    }
  }
}

// ---------------- QKV GEMM with fused RoPE epilogue ----------------
// z=0: Q (rope + 0.125 pre-scale), z=1: K (rope), z=2: V (plain).
// RoPE pair (d even, d odd) = adjacent output columns = adjacent lanes:
// partner value via __shfl_xor(v, 1).
struct QkvArgs {
  const ushort_t* A;
  const ushort_t* Bq; const ushort_t* Bk; const ushort_t* Bv;
  ushort_t* Cq; ushort_t* Ck; ushort_t* Cv;
};

__global__ __launch_bounds__(256) void gemm_qkv(QkvArgs args) {
  const int z = blockIdx.z;
  const ushort_t* B = z == 0 ? args.Bq : (z == 1 ? args.Bk : args.Bv);
  ushort_t* C = z == 0 ? args.Cq : (z == 1 ? args.Ck : args.Cv);
  __shared__ __align__(16) ushort_t sA[128 * 32];
  __shared__ __align__(16) ushort_t sB[128 * 32];
  GEMM_KLOOP(args.A, B, 0, D_MODEL, D_MODEL)
  if (z == 2) {
#pragma unroll
    for (int mi = 0; mi < 4; mi++) {
      int r0 = bm + waveM + mi * 16 + quad * 4;
#pragma unroll
      for (int ni = 0; ni < 4; ni++) {
        int c0 = bn + waveN + ni * 16 + col;
#pragma unroll
        for (int r = 0; r < 4; r++)
          C[(size_t)(r0 + r) * D_MODEL + c0] = f2bf(acc[mi][ni][r]);
      }
    }
  } else {
    const float qscale = (z == 0) ? 0.125f : 1.0f;
#pragma unroll
    for (int ni = 0; ni < 4; ni++) {
      const int c0 = bn + waveN + ni * 16 + col;
      const int d = c0 & 63;                 // position within head
      const int pr = d >> 1;
      const float inv = expf(-(float)pr * (9.210340372f / 32.0f));
      const float sgn = (c0 & 1) ? 1.0f : -1.0f;   // even: -partner*sin, odd: +partner*sin
#pragma unroll
      for (int mi = 0; mi < 4; mi++) {
        int r0 = bm + waveM + mi * 16 + quad * 4;
#pragma unroll
        for (int r = 0; r < 4; r++) {
          int s = (r0 + r) & (SEQ - 1);
          float ang = (float)s * inv;
          float cs = cosf(ang), sn = sinf(ang);
          float v = acc[mi][ni][r];
          float partner = __shfl_xor(v, 1);
          float res = (v * cs + sgn * partner * sn) * qscale;
          C[(size_t)(r0 + r) * D_MODEL + c0] = f2bf(res);
        }
      }
    }
  }
}

// ---------------- FFN13 GEMM with fused SwiGLU epilogue ----------------
// B13 = W1/W3 row-interleaved [5632,1024]: even rows W1 (u), odd rows W3 (g).
// Even lanes hold u, odd lanes hold g for the same output element; pair via
// shfl_xor(1), even lanes store silu(u)*g to C[4096,2816] bf16.
__global__ __launch_bounds__(256) void gemm_ffn13(
    const ushort_t* __restrict__ A, const ushort_t* __restrict__ B13,
    ushort_t* __restrict__ C) {
  __shared__ __align__(16) ushort_t sA[128 * 32];
  __shared__ __align__(16) ushort_t sB[128 * 32];
  GEMM_KLOOP(A, B13, 0, D_MODEL, D_MODEL)
  const bool is_u = (lane & 1) == 0;
#pragma unroll
  for (int mi = 0; mi < 4; mi++) {
    int r0 = bm + waveM + mi * 16 + quad * 4;
#pragma unroll
    for (int ni = 0; ni < 4; ni++) {
      int c0 = bn + waveN + ni * 16 + col;
      int oc = c0 >> 1;
#pragma unroll
      for (int r = 0; r < 4; r++) {
        float v = acc[mi][ni][r];
        float partner = __shfl_xor(v, 1);
        if (is_u) {
          float s = v / (1.f + __expf(-v)) * partner;
          C[(size_t)(r0 + r) * D_FF + oc] = f2bf(s);
        }
      }
    }
  }
}

// ---------------- V transpose: [B,S,H*dk] -> [B,H,dk,S] ----------------
__global__ __launch_bounds__(256) void vtrans_kernel(
    const ushort_t* __restrict__ v, ushort_t* __restrict__ vt) {
  int bh = blockIdx.y;
  int b = bh >> 4, h = bh & 15;
  int s0 = blockIdx.x * 64;
  __shared__ ushort_t tile[64][65];
  for (int i = threadIdx.x; i < 64 * 64; i += 256) {
    int sl = i >> 6, dl = i & 63;
    tile[dl][sl] = v[((size_t)(b * SEQ + s0 + sl)) * D_MODEL + h * DK + dl];
  }
  __syncthreads();
  for (int i = threadIdx.x; i < 64 * 64; i += 256) {
    int dl = i >> 6, sl = i & 63;
    vt[((size_t)bh * DK + dl) * SEQ + s0 + sl] = tile[dl][sl];
  }
}

// ---------------- flash attention, causal, q-tile 32, XCD-swizzled, pipelined ----------------
struct WaveMem {
  union {
    struct {
      ushort_t pbuf[32][72];
      float abuf[32];
    } s;
    float obuf[2][4][64][4];
  };
};

__global__ __launch_bounds__(256) void attn_kernel(
    const ushort_t* __restrict__ q, const ushort_t* __restrict__ k,
    const ushort_t* __restrict__ vt, ushort_t* __restrict__ out) {
  const int bidx = blockIdx.x;
  const int bh = bidx & 31;              // head -> XCD affinity via %8
  const int b = bh >> 4, h = bh & 15;
  const int t = 63 - (bidx >> 5);        // longest-first
  const int s0 = t * 32;
  const int w = threadIdx.x >> 6, lane = threadIdx.x & 63;
  const int col = lane & 15, quad = lane >> 4;
  const size_t base = ((size_t)(b * SEQ)) * D_MODEL + h * DK;

  short8 qf[2][2];
#pragma unroll
  for (int qh = 0; qh < 2; qh++)
#pragma unroll
    for (int kk = 0; kk < 2; kk++)
      qf[qh][kk] = *(const short8*)&q[base + (size_t)(s0 + qh * 16 + col) * D_MODEL + kk * 32 + quad * 8];

  f32x4 o[2][4] = {};
  float m_i[2] = {-__builtin_inff(), -__builtin_inff()};
  float l_i[2] = {0.f, 0.f};

  __shared__ __align__(16) WaveMem wmem[4];
  __shared__ float mbuf[4][32];
  __shared__ float lbuf[4][32];
  WaveMem& wm = wmem[w];

  const int ntiles = (s0 + 32 + 63) >> 6;
  short8 kf[2][4];
  if (w < ntiles) {
    const int skey = w * 64;
#pragma unroll
    for (int kk = 0; kk < 2; kk++)
#pragma unroll
      for (int sub = 0; sub < 4; sub++)
        kf[kk][sub] = *(const short8*)&k[base + (size_t)(skey + sub * 16 + col) * D_MODEL + kk * 32 + quad * 8];
  }

  for (int jt = w; jt < ntiles; jt += 4) {
    const int skey = jt * 64;
    short8 vf[4][2];
#pragma unroll
    for (int c2 = 0; c2 < 4; c2++) {
      const ushort_t* vrow = &vt[((size_t)bh * DK + c2 * 16 + col) * SEQ + skey];
      vf[c2][0] = *(const short8*)&vrow[quad * 8];
      vf[c2][1] = *(const short8*)&vrow[32 + quad * 8];
    }
    f32x4 S[2][4] = {};
#pragma unroll
    for (int kk = 0; kk < 2; kk++) {
#pragma unroll
      for (int sub = 0; sub < 4; sub++) {
        S[0][sub] = __builtin_amdgcn_mfma_f32_16x16x32_bf16(kf[kk][sub], qf[0][kk], S[0][sub], 0, 0, 0);
        S[1][sub] = __builtin_amdgcn_mfma_f32_16x16x32_bf16(kf[kk][sub], qf[1][kk], S[1][sub], 0, 0, 0);
      }
    }
    const int jn = jt + 4;
    if (jn < ntiles) {
      const int skn = jn * 64;
#pragma unroll
      for (int kk = 0; kk < 2; kk++)
#pragma unroll
        for (int sub = 0; sub < 4; sub++)
          kf[kk][sub] = *(const short8*)&k[base + (size_t)(skn + sub * 16 + col) * D_MODEL + kk * 32 + quad * 8];
    }
    float sv[2][4][4];
#pragma unroll
    for (int qh = 0; qh < 2; qh++)
#pragma unroll
      for (int sub = 0; sub < 4; sub++)
#pragma unroll
        for (int r = 0; r < 4; r++) sv[qh][sub][r] = S[qh][sub][r];
    if (skey + 63 > s0) {
#pragma unroll
      for (int qh = 0; qh < 2; qh++) {
        const int kb = skey + quad * 4 - s0 - qh * 16 - col;
#pragma unroll
        for (int sub = 0; sub < 4; sub++)
#pragma unroll
          for (int r = 0; r < 4; r++)
            if (kb + sub * 16 + r > 0) sv[qh][sub][r] = -__builtin_inff();
      }
    }
#pragma unroll
    for (int qh = 0; qh < 2; qh++) {
      float mt = sv[qh][0][0];
#pragma unroll
      for (int sub = 0; sub < 4; sub++)
#pragma unroll
        for (int r = 0; r < 4; r++) mt = fmaxf(mt, sv[qh][sub][r]);
      mt = fmaxf(mt, __shfl_xor(mt, 16));
      mt = fmaxf(mt, __shfl_xor(mt, 32));
      const float mn = fmaxf(m_i[qh], mt);
      const float alpha = __expf(m_i[qh] - mn);
      m_i[qh] = mn;
      float p[4][4];
      float ps = 0.f;
#pragma unroll
      for (int sub = 0; sub < 4; sub++)
#pragma unroll
        for (int r = 0; r < 4; r++) { p[sub][r] = __expf(sv[qh][sub][r] - mn); ps += p[sub][r]; }
      ps += __shfl_xor(ps, 16);
      ps += __shfl_xor(ps, 32);
      l_i[qh] = alpha * l_i[qh] + ps;
#pragma unroll
      for (int sub = 0; sub < 4; sub++) {
        ushort4 pk;
        pk.x = f2bf(p[sub][0]); pk.y = f2bf(p[sub][1]);
        pk.z = f2bf(p[sub][2]); pk.w = f2bf(p[sub][3]);
        *(ushort4*)&wm.s.pbuf[qh * 16 + col][sub * 16 + quad * 4] = pk;
      }
      if (quad == 0) wm.s.abuf[qh * 16 + col] = alpha;
    }
    __builtin_amdgcn_s_waitcnt(0xC07F);   // lgkmcnt(0): own-wave LDS visible
    const f32x4 av0 = *(const f32x4*)&wm.s.abuf[quad * 4];
    const f32x4 av1 = *(const f32x4*)&wm.s.abuf[16 + quad * 4];
    short8 pf[2][2];
#pragma unroll
    for (int qh = 0; qh < 2; qh++) {
      pf[qh][0] = *(const short8*)&wm.s.pbuf[qh * 16 + col][quad * 8];
      pf[qh][1] = *(const short8*)&wm.s.pbuf[qh * 16 + col][32 + quad * 8];
    }
#pragma unroll
    for (int c2 = 0; c2 < 4; c2++) {
#pragma unroll
      for (int r = 0; r < 4; r++) { o[0][c2][r] *= av0[r]; o[1][c2][r] *= av1[r]; }
      o[0][c2] = __builtin_amdgcn_mfma_f32_16x16x32_bf16(pf[0][0], vf[c2][0], o[0][c2], 0, 0, 0);
      o[0][c2] = __builtin_amdgcn_mfma_f32_16x16x32_bf16(pf[0][1], vf[c2][1], o[0][c2], 0, 0, 0);
      o[1][c2] = __builtin_amdgcn_mfma_f32_16x16x32_bf16(pf[1][0], vf[c2][0], o[1][c2], 0, 0, 0);
      o[1][c2] = __builtin_amdgcn_mfma_f32_16x16x32_bf16(pf[1][1], vf[c2][1], o[1][c2], 0, 0, 0);
    }
  }

#pragma unroll
  for (int qh = 0; qh < 2; qh++)
#pragma unroll
    for (int c2 = 0; c2 < 4; c2++)
      *(f32x4*)&wm.obuf[qh][c2][lane][0] = o[qh][c2];
  if (quad == 0) {
    mbuf[w][col]      = m_i[0];  mbuf[w][16 + col] = m_i[1];
    lbuf[w][col]      = l_i[0];  lbuf[w][16 + col] = l_i[1];
  }
  __syncthreads();

#pragma unroll
  for (int qh = 0; qh < 2; qh++) {
    float M[4], L[4], sc[4][4];
#pragma unroll
    for (int r = 0; r < 4; r++) {
      int row = qh * 16 + quad * 4 + r;
      float m0 = mbuf[0][row], m1 = mbuf[1][row], m2 = mbuf[2][row], m3 = mbuf[3][row];
      M[r] = fmaxf(fmaxf(m0, m1), fmaxf(m2, m3));
      float e0 = __expf(m0 - M[r]);
      float e1 = __expf(m1 - M[r]);
      float e2 = __expf(m2 - M[r]);
      float e3 = __expf(m3 - M[r]);
      sc[0][r] = e0; sc[1][r] = e1; sc[2][r] = e2; sc[3][r] = e3;
      L[r] = lbuf[0][row] * e0 + lbuf[1][row] * e1 + lbuf[2][row] * e2 + lbuf[3][row] * e3;
    }
    f32x4 oo = {};
#pragma unroll
    for (int wp = 0; wp < 4; wp++) {
      f32x4 tv = *(const f32x4*)&wmem[wp].obuf[qh][w][lane][0];
#pragma unroll
      for (int r = 0; r < 4; r++) oo[r] += tv[r] * sc[wp][r];
    }
#pragma unroll
    for (int r = 0; r < 4; r++) {
      int row = s0 + qh * 16 + quad * 4 + r;
      out[((size_t)(b * SEQ) + row) * D_MODEL + h * DK + w * 16 + col] = f2bf(oo[r] / L[r]);
    }
  }
}

// ---------------- launcher ----------------
extern "C" void kernel_launch(void* const* d_in, const int* in_sizes, int n_in,
                              void* d_out, int out_size, void* d_ws, size_t ws_size,
                              hipStream_t stream) {
  const float* x  = (const float*)d_in[0];
  const float* g1 = (const float*)d_in[1];
  const float* g2 = (const float*)d_in[2];
  const float* WQ = (const float*)d_in[3];
  const float* WK = (const float*)d_in[4];
  const float* WV = (const float*)d_in[5];
  const float* WO = (const float*)d_in[6];
  const float* W1 = (const float*)d_in[7];
  const float* W2 = (const float*)d_in[8];
  const float* W3 = (const float*)d_in[9];
  float* out = (float*)d_out;

  char* p = (char*)d_ws;
  auto alloc = [&](size_t bytes) {
    char* r = p; p += (bytes + 255) & ~(size_t)255; return r;
  };
  ushort_t* wq  = (ushort_t*)alloc((size_t)D_MODEL * D_MODEL * 2);
  ushort_t* wk  = (ushort_t*)alloc((size_t)D_MODEL * D_MODEL * 2);
  ushort_t* wv  = (ushort_t*)alloc((size_t)D_MODEL * D_MODEL * 2);
  ushort_t* wo  = (ushort_t*)alloc((size_t)D_MODEL * D_MODEL * 2);
  ushort_t* w13 = (ushort_t*)alloc((size_t)2 * D_FF * D_MODEL * 2);  // W1/W3 row-interleaved
  ushort_t* w2b = (ushort_t*)alloc((size_t)D_FF * D_MODEL * 2);
  ushort_t* h   = (ushort_t*)alloc((size_t)NTOK * D_MODEL * 2);
  ushort_t* qb  = (ushort_t*)alloc((size_t)NTOK * D_MODEL * 2);
  ushort_t* kb  = (ushort_t*)alloc((size_t)NTOK * D_MODEL * 2);
  ushort_t* vb  = (ushort_t*)alloc((size_t)NTOK * D_MODEL * 2);   // later reused as attn out
  ushort_t* vtb = (ushort_t*)alloc((size_t)NTOK * D_MODEL * 2);
  float*    y   = (float*)   alloc((size_t)NTOK * D_MODEL * 4);
  ushort_t* ub  = (ushort_t*)alloc((size_t)NTOK * D_FF * 2);      // silu(u)*g
  float*    part = (float*)  alloc((size_t)4 * NTOK * D_MODEL * 4);
  const bool use_split = ((size_t)(p - (char*)d_ws) <= ws_size);

  // ---- weight converts: one launch; W1/W3 interleave into w13 ----
  const int nb_dd = D_MODEL * D_MODEL / 4 / 256;   // 1024
  const int nb_fd = D_FF * D_MODEL / 4 / 256;      // 2816
  CvtArgs ca;
  ca.src[0]=WQ; ca.dst[0]=wq;  ca.nblk[0]=nb_dd; ca.mul[0]=1; ca.ofs[0]=0;
  ca.src[1]=WK; ca.dst[1]=wk;  ca.nblk[1]=nb_dd; ca.mul[1]=1; ca.ofs[1]=0;
  ca.src[2]=WV; ca.dst[2]=wv;  ca.nblk[2]=nb_dd; ca.mul[2]=1; ca.ofs[2]=0;
  ca.src[3]=WO; ca.dst[3]=wo;  ca.nblk[3]=nb_dd; ca.mul[3]=1; ca.ofs[3]=0;
  ca.src[4]=W1; ca.dst[4]=w13; ca.nblk[4]=nb_fd; ca.mul[4]=2; ca.ofs[4]=0;
  ca.src[5]=W3; ca.dst[5]=w13; ca.nblk[5]=nb_fd; ca.mul[5]=2; ca.ofs[5]=1;
  ca.src[6]=W2; ca.dst[6]=w2b; ca.nblk[6]=nb_fd; ca.mul[6]=1; ca.ofs[6]=0;
  convert_all<<<4 * nb_dd + 3 * nb_fd, 256, 0, stream>>>(ca);

  rmsnorm_kernel<<<NTOK, 256, 0, stream>>>(x, g1, h);

  QkvArgs qa{h, wq, wk, wv, qb, kb, vb};
  gemm_qkv<<<dim3(D_MODEL / 128, NTOK / 128, 3), 256, 0, stream>>>(qa);

  vtrans_kernel<<<dim3(SEQ / 64, BATCH * NHEADS), 256, 0, stream>>>(vb, vtb);
  attn_kernel<<<dim3((SEQ / 32) * 32, 1), 256, 0, stream>>>(qb, kb, vtb, vb);

  if (use_split) {
    GemmSplitArgs s1{vb, wo, part, D_MODEL, D_MODEL, D_MODEL / 4};
    gemm128_splitk<<<dim3(D_MODEL / 128, NTOK / 128, 4), 256, 0, stream>>>(s1);
    rmsnorm_reduce4<<<NTOK, 256, 0, stream>>>(part, x, g2, y, h);
  } else {
    GemmArgs a2{vb, wo, nullptr, nullptr, y, nullptr, nullptr, x, NTOK, D_MODEL, D_MODEL};
    gemm128<1><<<dim3(D_MODEL / 128, NTOK / 128, 1), 256, 0, stream>>>(a2);
    rmsnorm_kernel<<<NTOK, 256, 0, stream>>>(y, g2, h);
  }

  gemm_ffn13<<<dim3(2 * D_FF / 128, NTOK / 128), 256, 0, stream>>>(h, w13, ub);

  if (use_split) {
    GemmSplitArgs s2{ub, w2b, part, D_MODEL, D_FF, D_FF / 4};
    gemm128_splitk<<<dim3(D_MODEL / 128, NTOK / 128, 4), 256, 0, stream>>>(s2);
    add_reduce4<<<NTOK * D_MODEL / 4 / 256, 256, 0, stream>>>(part, y, out);
  } else {
    GemmArgs a4{ub, w2b, nullptr, nullptr, out, nullptr, nullptr, y, NTOK, D_MODEL, D_FF};
    gemm128<1><<<dim3(D_MODEL / 128, NTOK / 128, 1), 256, 0, stream>>>(a4);
  }
}

// Round 8
// 412.661 us; speedup vs baseline: 1.8592x; 1.8592x over previous
//
#include <hip/hip_runtime.h>
#include <cstdint>
#include <cstddef>

typedef short short8 __attribute__((ext_vector_type(8)));
typedef float f32x4 __attribute__((ext_vector_type(4)));
typedef unsigned short ushort_t;

#define D_MODEL 1024
#define D_FF    2816
#define SEQ     2048
#define BATCH   2
#define NHEADS  16
#define DK      64
#define NTOK    (BATCH*SEQ)   // 4096

__device__ __forceinline__ float bf2f(ushort_t u) {
  return __builtin_bit_cast(float, (unsigned int)u << 16);
}
__device__ __forceinline__ ushort_t f2bf(float f) {
  unsigned int x = __builtin_bit_cast(unsigned int, f);
  x += 0x7fffu + ((x >> 16) & 1u);   // round-to-nearest-even
  return (ushort_t)(x >> 16);
}

// async global->LDS, 16B per lane. LDS dest = wave-uniform base + lane*16.
__device__ __forceinline__ void gld16(const ushort_t* g, ushort_t* l) {
  __builtin_amdgcn_global_load_lds(
      (const __attribute__((address_space(1))) unsigned int*)g,
      (__attribute__((address_space(3))) unsigned int*)l,
      16, 0, 0);
}

// ---------------- fp32 -> bf16 convert, all 7 weights in one launch ----------------
// mul/ofs remap rows for the W1/W3 interleave: dst row = src_row*mul + ofs.
struct CvtArgs {
  const float* src[7];
  ushort_t* dst[7];
  int nblk[7];
  int mul[7];
  int ofs[7];
};
__global__ __launch_bounds__(256) void convert_all(CvtArgs a) {
  int off = blockIdx.x;
  int seg = 0;
  while (off >= a.nblk[seg]) { off -= a.nblk[seg]; seg++; }   // wave-uniform
  int i = off * 256 + threadIdx.x;
  int row = i >> 8, c = i & 255;
  float4 v = ((const float4*)a.src[seg])[i];
  ushort4 o;
  o.x = f2bf(v.x); o.y = f2bf(v.y); o.z = f2bf(v.z); o.w = f2bf(v.w);
  ((ushort4*)a.dst[seg])[(size_t)(row * a.mul[seg] + a.ofs[seg]) * 256 + c] = o;
}

// ---------------- RMSNorm (row of 1024) ----------------
__global__ __launch_bounds__(256) void rmsnorm_kernel(
    const float* __restrict__ x, const float* __restrict__ g, ushort_t* __restrict__ out) {
  int row = blockIdx.x;
  int tid = threadIdx.x;
  float4 v = ((const float4*)(x + (size_t)row * D_MODEL))[tid];
  float ss = v.x*v.x + v.y*v.y + v.z*v.z + v.w*v.w;
#pragma unroll
  for (int off = 1; off < 64; off <<= 1) ss += __shfl_xor(ss, off);
  __shared__ float wsum[4];
  if ((tid & 63) == 0) wsum[tid >> 6] = ss;
  __syncthreads();
  float total = wsum[0] + wsum[1] + wsum[2] + wsum[3];
  float rinv = rsqrtf(total * (1.0f / D_MODEL) + 1e-5f);
  float4 gv = ((const float4*)g)[tid];
  ushort4 o;
  o.x = f2bf(v.x * gv.x * rinv);
  o.y = f2bf(v.y * gv.y * rinv);
  o.z = f2bf(v.z * gv.z * rinv);
  o.w = f2bf(v.w * gv.w * rinv);
  ((ushort4*)(out + (size_t)row * D_MODEL))[tid] = o;
}

// ---- y = sum(4 partials) + x; h = rmsnorm(y)*g  (fused WO split-K reduce) ----
__global__ __launch_bounds__(256) void rmsnorm_reduce4(
    const float* __restrict__ part, const float* __restrict__ x,
    const float* __restrict__ g, float* __restrict__ y, ushort_t* __restrict__ h) {
  const int row = blockIdx.x;
  const int tid = threadIdx.x;
  const size_t i = (size_t)row * 256 + tid;           // float4 index
  const size_t MN4 = (size_t)NTOK * (D_MODEL / 4);
  float4 v = ((const float4*)x)[i];
#pragma unroll
  for (int jp = 0; jp < 4; jp++) {
    float4 pv = ((const float4*)part)[jp * MN4 + i];
    v.x += pv.x; v.y += pv.y; v.z += pv.z; v.w += pv.w;
  }
  ((float4*)y)[i] = v;
  float ss = v.x*v.x + v.y*v.y + v.z*v.z + v.w*v.w;
#pragma unroll
  for (int off = 1; off < 64; off <<= 1) ss += __shfl_xor(ss, off);
  __shared__ float wsum[4];
  if ((tid & 63) == 0) wsum[tid >> 6] = ss;
  __syncthreads();
  float total = wsum[0] + wsum[1] + wsum[2] + wsum[3];
  float rinv = rsqrtf(total * (1.0f / D_MODEL) + 1e-5f);
  float4 gv = ((const float4*)g)[tid];
  ushort4 o;
  o.x = f2bf(v.x * gv.x * rinv);
  o.y = f2bf(v.y * gv.y * rinv);
  o.z = f2bf(v.z * gv.z * rinv);
  o.w = f2bf(v.w * gv.w * rinv);
  ((ushort4*)(h + (size_t)row * D_MODEL))[tid] = o;
}

// ---- out = sum(4 partials) + y  (W2 split-K reduce + final residual) ----
__global__ __launch_bounds__(256) void add_reduce4(
    const float* __restrict__ part, const float* __restrict__ y, float* __restrict__ out) {
  const size_t i = (size_t)blockIdx.x * 256 + threadIdx.x;
  const size_t MN4 = (size_t)NTOK * (D_MODEL / 4);
  float4 v = ((const float4*)y)[i];
#pragma unroll
  for (int jp = 0; jp < 4; jp++) {
    float4 pv = ((const float4*)part)[jp * MN4 + i];
    v.x += pv.x; v.y += pv.y; v.z += pv.z; v.w += pv.w;
  }
  ((float4*)out)[i] = v;
}

// ======== shared K-loop macro body (m97 structure): fills acc[4][4] ========
#define GEMM_KLOOP(Aptr, Bptr, KBEG, KEND, KSTRIDE)                              \
  const int tid  = threadIdx.x;                                                  \
  const int w    = tid >> 6;                                                     \
  const int lane = tid & 63;                                                     \
  const int col  = lane & 15;                                                    \
  const int quad = lane >> 4;                                                    \
  const int waveM = (w >> 1) * 64;                                               \
  const int waveN = (w & 1) * 64;                                                \
  const int bm = blockIdx.y * 128;                                               \
  const int bn = blockIdx.x * 128;                                               \
  f32x4 acc[4][4] = {};                                                          \
  {                                                                              \
    const int srow = tid >> 2;                                                   \
    const int scol = (tid & 3) * 8;                                              \
    const ushort_t* gA = (Aptr) + (size_t)(bm + srow) * (KSTRIDE) + scol;        \
    const ushort_t* gB = (Bptr) + (size_t)(bn + srow) * (KSTRIDE) + scol;        \
    ushort_t* lA = sA + tid * 8;                                                 \
    ushort_t* lB = sB + tid * 8;                                                 \
    const size_t rstep = (size_t)64 * (KSTRIDE);                                 \
    for (int k0 = (KBEG); k0 < (KEND); k0 += 32) {                               \
      gld16(gA + k0,         lA);                                                \
      gld16(gA + k0 + rstep, lA + 2048);                                         \
      gld16(gB + k0,         lB);                                                \
      gld16(gB + k0 + rstep, lB + 2048);                                         \
      __syncthreads();                                                           \
      short8 af[4], bfm[4];                                                      \
      _Pragma("unroll")                                                          \
      for (int mi = 0; mi < 4; mi++)                                             \
        af[mi] = *(const short8*)&sA[(waveM + mi * 16 + col) * 32 + quad * 8];   \
      _Pragma("unroll")                                                          \
      for (int ni = 0; ni < 4; ni++)                                             \
        bfm[ni] = *(const short8*)&sB[(waveN + ni * 16 + col) * 32 + quad * 8];  \
      _Pragma("unroll")                                                          \
      for (int mi = 0; mi < 4; mi++)                                             \
        _Pragma("unroll")                                                        \
        for (int ni = 0; ni < 4; ni++)                                           \
          acc[mi][ni] = __builtin_amdgcn_mfma_f32_16x16x32_bf16(af[mi], bfm[ni], acc[mi][ni], 0, 0, 0); \
      __syncthreads();                                                           \
    }                                                                            \
  }

// ---------------- generic GEMM (EPI 0: bf16 store; 1: fp32 + resid) ----------------
struct GemmArgs {
  const ushort_t* A;
  const ushort_t* B0; const ushort_t* B1; const ushort_t* B2;
  void* C0; void* C1; void* C2;
  const float* resid;
  int M, N, K;
};

template<int EPI>
__global__ __launch_bounds__(256) void gemm128(GemmArgs args) {
  const ushort_t* B = blockIdx.z == 0 ? args.B0 : (blockIdx.z == 1 ? args.B1 : args.B2);
  void* C = blockIdx.z == 0 ? args.C0 : (blockIdx.z == 1 ? args.C1 : args.C2);
  const int N = args.N, K = args.K;
  __shared__ __align__(16) ushort_t sA[128 * 32];
  __shared__ __align__(16) ushort_t sB[128 * 32];
  GEMM_KLOOP(args.A, B, 0, K, K)
#pragma unroll
  for (int mi = 0; mi < 4; mi++) {
    int r0 = bm + waveM + mi * 16 + quad * 4;
#pragma unroll
    for (int ni = 0; ni < 4; ni++) {
      int c0 = bn + waveN + ni * 16 + col;
#pragma unroll
      for (int r = 0; r < 4; r++) {
        size_t idx = (size_t)(r0 + r) * N + c0;
        if (EPI == 0) ((ushort_t*)C)[idx] = f2bf(acc[mi][ni][r]);
        else          ((float*)C)[idx]    = acc[mi][ni][r] + args.resid[idx];
      }
    }
  }
}

// ---- split-K variant: grid.z = 4 K-chunks, fp32 partials to C[z][M*N] ----
struct GemmSplitArgs {
  const ushort_t* A; const ushort_t* B;
  float* C;
  int N, K, kchunk;
};

__global__ __launch_bounds__(256) void gemm128_splitk(GemmSplitArgs args) {
  const int N = args.N, K = args.K;
  const int kbeg = blockIdx.z * args.kchunk;
  const int kend = kbeg + args.kchunk;
  __shared__ __align__(16) ushort_t sA[128 * 32];
  __shared__ __align__(16) ushort_t sB[128 * 32];
  GEMM_KLOOP(args.A, args.B, kbeg, kend, K)
  float* C = args.C + (size_t)blockIdx.z * ((size_t)NTOK * N);
#pragma unroll
  for (int mi = 0; mi < 4; mi++) {
    int r0 = bm + waveM + mi * 16 + quad * 4;
#pragma unroll
    for (int ni = 0; ni < 4; ni++) {
      int c0 = bn + waveN + ni * 16 + col;
#pragma unroll
      for (int r = 0; r < 4; r++)
        C[(size_t)(r0 + r) * N + c0] = acc[mi][ni][r];
    }
  }
}

// ---------------- QKV GEMM with fused RoPE epilogue ----------------
// z=0: Q (rope + 0.125 pre-scale), z=1: K (rope), z=2: V (plain).
// RoPE pair = adjacent output columns = adjacent lanes: partner via shfl_xor(1).
// Trig via HARDWARE __cosf/__sinf/exp2f ONLY (v_cos/v_sin/v_exp) — OCML
// cosf/sinf here spilled acc[4][4] to scratch: 1.4 GB of HBM writes (round 7).
struct QkvArgs {
  const ushort_t* A;
  const ushort_t* Bq; const ushort_t* Bk; const ushort_t* Bv;
  ushort_t* Cq; ushort_t* Ck; ushort_t* Cv;
};

__global__ __launch_bounds__(256) void gemm_qkv(QkvArgs args) {
  const int z = blockIdx.z;
  const ushort_t* B = z == 0 ? args.Bq : (z == 1 ? args.Bk : args.Bv);
  ushort_t* C = z == 0 ? args.Cq : (z == 1 ? args.Ck : args.Cv);
  __shared__ __align__(16) ushort_t sA[128 * 32];
  __shared__ __align__(16) ushort_t sB[128 * 32];
  GEMM_KLOOP(args.A, B, 0, D_MODEL, D_MODEL)
  if (z == 2) {
#pragma unroll
    for (int mi = 0; mi < 4; mi++) {
      int r0 = bm + waveM + mi * 16 + quad * 4;
#pragma unroll
      for (int ni = 0; ni < 4; ni++) {
        int c0 = bn + waveN + ni * 16 + col;
#pragma unroll
        for (int r = 0; r < 4; r++)
          C[(size_t)(r0 + r) * D_MODEL + c0] = f2bf(acc[mi][ni][r]);
      }
    }
  } else {
    const float qscale = (z == 0) ? 0.125f : 1.0f;
#pragma unroll
    for (int ni = 0; ni < 4; ni++) {
      const int c0 = bn + waveN + ni * 16 + col;
      const int pr = (c0 & 63) >> 1;           // rotary pair index within head
      // inv = 10000^(-pr/32) = 2^(-pr * log2(10000)/32); exp2f -> v_exp_f32
      const float inv = exp2f(-(float)pr * 0.41524101186f);
      const float sgn = (c0 & 1) ? 1.0f : -1.0f;   // even: -partner*sin, odd: +partner*sin
#pragma unroll
      for (int mi = 0; mi < 4; mi++) {
        int r0 = bm + waveM + mi * 16 + quad * 4;
#pragma unroll
        for (int r = 0; r < 4; r++) {
          int s = (r0 + r) & (SEQ - 1);
          float ang = (float)s * inv;
          float cs = __cosf(ang), sn = __sinf(ang);   // v_cos/v_sin, no scratch
          float v = acc[mi][ni][r];
          float partner = __shfl_xor(v, 1);
          float res = (v * cs + sgn * partner * sn) * qscale;
          C[(size_t)(r0 + r) * D_MODEL + c0] = f2bf(res);
        }
      }
    }
  }
}

// ---------------- FFN13 GEMM with fused SwiGLU epilogue ----------------
// B13 = W1/W3 row-interleaved [5632,1024]: even rows W1 (u), odd rows W3 (g).
// Even lanes hold u, odd lanes hold g; pair via shfl_xor(1); even lanes store
// silu(u)*g to C[4096,2816] bf16.
__global__ __launch_bounds__(256) void gemm_ffn13(
    const ushort_t* __restrict__ A, const ushort_t* __restrict__ B13,
    ushort_t* __restrict__ C) {
  __shared__ __align__(16) ushort_t sA[128 * 32];
  __shared__ __align__(16) ushort_t sB[128 * 32];
  GEMM_KLOOP(A, B13, 0, D_MODEL, D_MODEL)
  const bool is_u = (lane & 1) == 0;
#pragma unroll
  for (int mi = 0; mi < 4; mi++) {
    int r0 = bm + waveM + mi * 16 + quad * 4;
#pragma unroll
    for (int ni = 0; ni < 4; ni++) {
      int c0 = bn + waveN + ni * 16 + col;
      int oc = c0 >> 1;
#pragma unroll
      for (int r = 0; r < 4; r++) {
        float v = acc[mi][ni][r];
        float partner = __shfl_xor(v, 1);
        if (is_u) {
          float s = v / (1.f + __expf(-v)) * partner;
          C[(size_t)(r0 + r) * D_FF + oc] = f2bf(s);
        }
      }
    }
  }
}

// ---------------- V transpose: [B,S,H*dk] -> [B,H,dk,S] ----------------
__global__ __launch_bounds__(256) void vtrans_kernel(
    const ushort_t* __restrict__ v, ushort_t* __restrict__ vt) {
  int bh = blockIdx.y;
  int b = bh >> 4, h = bh & 15;
  int s0 = blockIdx.x * 64;
  __shared__ ushort_t tile[64][65];
  for (int i = threadIdx.x; i < 64 * 64; i += 256) {
    int sl = i >> 6, dl = i & 63;
    tile[dl][sl] = v[((size_t)(b * SEQ + s0 + sl)) * D_MODEL + h * DK + dl];
  }
  __syncthreads();
  for (int i = threadIdx.x; i < 64 * 64; i += 256) {
    int dl = i >> 6, sl = i & 63;
    vt[((size_t)bh * DK + dl) * SEQ + s0 + sl] = tile[dl][sl];
  }
}

// ---------------- flash attention, causal, q-tile 32, XCD-swizzled, pipelined ----------------
struct WaveMem {
  union {
    struct {
      ushort_t pbuf[32][72];
      float abuf[32];
    } s;
    float obuf[2][4][64][4];
  };
};

__global__ __launch_bounds__(256) void attn_kernel(
    const ushort_t* __restrict__ q, const ushort_t* __restrict__ k,
    const ushort_t* __restrict__ vt, ushort_t* __restrict__ out) {
  const int bidx = blockIdx.x;
  const int bh = bidx & 31;              // head -> XCD affinity via %8
  const int b = bh >> 4, h = bh & 15;
  const int t = 63 - (bidx >> 5);        // longest-first
  const int s0 = t * 32;
  const int w = threadIdx.x >> 6, lane = threadIdx.x & 63;
  const int col = lane & 15, quad = lane >> 4;
  const size_t base = ((size_t)(b * SEQ)) * D_MODEL + h * DK;

  short8 qf[2][2];
#pragma unroll
  for (int qh = 0; qh < 2; qh++)
#pragma unroll
    for (int kk = 0; kk < 2; kk++)
      qf[qh][kk] = *(const short8*)&q[base + (size_t)(s0 + qh * 16 + col) * D_MODEL + kk * 32 + quad * 8];

  f32x4 o[2][4] = {};
  float m_i[2] = {-__builtin_inff(), -__builtin_inff()};
  float l_i[2] = {0.f, 0.f};

  __shared__ __align__(16) WaveMem wmem[4];
  __shared__ float mbuf[4][32];
  __shared__ float lbuf[4][32];
  WaveMem& wm = wmem[w];

  const int ntiles = (s0 + 32 + 63) >> 6;
  short8 kf[2][4];
  if (w < ntiles) {
    const int skey = w * 64;
#pragma unroll
    for (int kk = 0; kk < 2; kk++)
#pragma unroll
      for (int sub = 0; sub < 4; sub++)
        kf[kk][sub] = *(const short8*)&k[base + (size_t)(skey + sub * 16 + col) * D_MODEL + kk * 32 + quad * 8];
  }

  for (int jt = w; jt < ntiles; jt += 4) {
    const int skey = jt * 64;
    short8 vf[4][2];
#pragma unroll
    for (int c2 = 0; c2 < 4; c2++) {
      const ushort_t* vrow = &vt[((size_t)bh * DK + c2 * 16 + col) * SEQ + skey];
      vf[c2][0] = *(const short8*)&vrow[quad * 8];
      vf[c2][1] = *(const short8*)&vrow[32 + quad * 8];
    }
    f32x4 S[2][4] = {};
#pragma unroll
    for (int kk = 0; kk < 2; kk++) {
#pragma unroll
      for (int sub = 0; sub < 4; sub++) {
        S[0][sub] = __builtin_amdgcn_mfma_f32_16x16x32_bf16(kf[kk][sub], qf[0][kk], S[0][sub], 0, 0, 0);
        S[1][sub] = __builtin_amdgcn_mfma_f32_16x16x32_bf16(kf[kk][sub], qf[1][kk], S[1][sub], 0, 0, 0);
      }
    }
    const int jn = jt + 4;
    if (jn < ntiles) {
      const int skn = jn * 64;
#pragma unroll
      for (int kk = 0; kk < 2; kk++)
#pragma unroll
        for (int sub = 0; sub < 4; sub++)
          kf[kk][sub] = *(const short8*)&k[base + (size_t)(skn + sub * 16 + col) * D_MODEL + kk * 32 + quad * 8];
    }
    float sv[2][4][4];
#pragma unroll
    for (int qh = 0; qh < 2; qh++)
#pragma unroll
      for (int sub = 0; sub < 4; sub++)
#pragma unroll
        for (int r = 0; r < 4; r++) sv[qh][sub][r] = S[qh][sub][r];
    if (skey + 63 > s0) {
#pragma unroll
      for (int qh = 0; qh < 2; qh++) {
        const int kb = skey + quad * 4 - s0 - qh * 16 - col;
#pragma unroll
        for (int sub = 0; sub < 4; sub++)
#pragma unroll
          for (int r = 0; r < 4; r++)
            if (kb + sub * 16 + r > 0) sv[qh][sub][r] = -__builtin_inff();
      }
    }
#pragma unroll
    for (int qh = 0; qh < 2; qh++) {
      float mt = sv[qh][0][0];
#pragma unroll
      for (int sub = 0; sub < 4; sub++)
#pragma unroll
        for (int r = 0; r < 4; r++) mt = fmaxf(mt, sv[qh][sub][r]);
      mt = fmaxf(mt, __shfl_xor(mt, 16));
      mt = fmaxf(mt, __shfl_xor(mt, 32));
      const float mn = fmaxf(m_i[qh], mt);
      const float alpha = __expf(m_i[qh] - mn);
      m_i[qh] = mn;
      float p[4][4];
      float ps = 0.f;
#pragma unroll
      for (int sub = 0; sub < 4; sub++)
#pragma unroll
        for (int r = 0; r < 4; r++) { p[sub][r] = __expf(sv[qh][sub][r] - mn); ps += p[sub][r]; }
      ps += __shfl_xor(ps, 16);
      ps += __shfl_xor(ps, 32);
      l_i[qh] = alpha * l_i[qh] + ps;
#pragma unroll
      for (int sub = 0; sub < 4; sub++) {
        ushort4 pk;
        pk.x = f2bf(p[sub][0]); pk.y = f2bf(p[sub][1]);
        pk.z = f2bf(p[sub][2]); pk.w = f2bf(p[sub][3]);
        *(ushort4*)&wm.s.pbuf[qh * 16 + col][sub * 16 + quad * 4] = pk;
      }
      if (quad == 0) wm.s.abuf[qh * 16 + col] = alpha;
    }
    __builtin_amdgcn_s_waitcnt(0xC07F);   // lgkmcnt(0): own-wave LDS visible
    const f32x4 av0 = *(const f32x4*)&wm.s.abuf[quad * 4];
    const f32x4 av1 = *(const f32x4*)&wm.s.abuf[16 + quad * 4];
    short8 pf[2][2];
#pragma unroll
    for (int qh = 0; qh < 2; qh++) {
      pf[qh][0] = *(const short8*)&wm.s.pbuf[qh * 16 + col][quad * 8];
      pf[qh][1] = *(const short8*)&wm.s.pbuf[qh * 16 + col][32 + quad * 8];
    }
#pragma unroll
    for (int c2 = 0; c2 < 4; c2++) {
#pragma unroll
      for (int r = 0; r < 4; r++) { o[0][c2][r] *= av0[r]; o[1][c2][r] *= av1[r]; }
      o[0][c2] = __builtin_amdgcn_mfma_f32_16x16x32_bf16(pf[0][0], vf[c2][0], o[0][c2], 0, 0, 0);
      o[0][c2] = __builtin_amdgcn_mfma_f32_16x16x32_bf16(pf[0][1], vf[c2][1], o[0][c2], 0, 0, 0);
      o[1][c2] = __builtin_amdgcn_mfma_f32_16x16x32_bf16(pf[1][0], vf[c2][0], o[1][c2], 0, 0, 0);
      o[1][c2] = __builtin_amdgcn_mfma_f32_16x16x32_bf16(pf[1][1], vf[c2][1], o[1][c2], 0, 0, 0);
    }
  }

#pragma unroll
  for (int qh = 0; qh < 2; qh++)
#pragma unroll
    for (int c2 = 0; c2 < 4; c2++)
      *(f32x4*)&wm.obuf[qh][c2][lane][0] = o[qh][c2];
  if (quad == 0) {
    mbuf[w][col]      = m_i[0];  mbuf[w][16 + col] = m_i[1];
    lbuf[w][col]      = l_i[0];  lbuf[w][16 + col] = l_i[1];
  }
  __syncthreads();

#pragma unroll
  for (int qh = 0; qh < 2; qh++) {
    float M[4], L[4], sc[4][4];
#pragma unroll
    for (int r = 0; r < 4; r++) {
      int row = qh * 16 + quad * 4 + r;
      float m0 = mbuf[0][row], m1 = mbuf[1][row], m2 = mbuf[2][row], m3 = mbuf[3][row];
      M[r] = fmaxf(fmaxf(m0, m1), fmaxf(m2, m3));
      float e0 = __expf(m0 - M[r]);
      float e1 = __expf(m1 - M[r]);
      float e2 = __expf(m2 - M[r]);
      float e3 = __expf(m3 - M[r]);
      sc[0][r] = e0; sc[1][r] = e1; sc[2][r] = e2; sc[3][r] = e3;
      L[r] = lbuf[0][row] * e0 + lbuf[1][row] * e1 + lbuf[2][row] * e2 + lbuf[3][row] * e3;
    }
    f32x4 oo = {};
#pragma unroll
    for (int wp = 0; wp < 4; wp++) {
      f32x4 tv = *(const f32x4*)&wmem[wp].obuf[qh][w][lane][0];
#pragma unroll
      for (int r = 0; r < 4; r++) oo[r] += tv[r] * sc[wp][r];
    }
#pragma unroll
    for (int r = 0; r < 4; r++) {
      int row = s0 + qh * 16 + quad * 4 + r;
      out[((size_t)(b * SEQ) + row) * D_MODEL + h * DK + w * 16 + col] = f2bf(oo[r] / L[r]);
    }
  }
}

// ---------------- launcher ----------------
extern "C" void kernel_launch(void* const* d_in, const int* in_sizes, int n_in,
                              void* d_out, int out_size, void* d_ws, size_t ws_size,
                              hipStream_t stream) {
  const float* x  = (const float*)d_in[0];
  const float* g1 = (const float*)d_in[1];
  const float* g2 = (const float*)d_in[2];
  const float* WQ = (const float*)d_in[3];
  const float* WK = (const float*)d_in[4];
  const float* WV = (const float*)d_in[5];
  const float* WO = (const float*)d_in[6];
  const float* W1 = (const float*)d_in[7];
  const float* W2 = (const float*)d_in[8];
  const float* W3 = (const float*)d_in[9];
  float* out = (float*)d_out;

  char* p = (char*)d_ws;
  auto alloc = [&](size_t bytes) {
    char* r = p; p += (bytes + 255) & ~(size_t)255; return r;
  };
  ushort_t* wq  = (ushort_t*)alloc((size_t)D_MODEL * D_MODEL * 2);
  ushort_t* wk  = (ushort_t*)alloc((size_t)D_MODEL * D_MODEL * 2);
  ushort_t* wv  = (ushort_t*)alloc((size_t)D_MODEL * D_MODEL * 2);
  ushort_t* wo  = (ushort_t*)alloc((size_t)D_MODEL * D_MODEL * 2);
  ushort_t* w13 = (ushort_t*)alloc((size_t)2 * D_FF * D_MODEL * 2);  // W1/W3 row-interleaved
  ushort_t* w2b = (ushort_t*)alloc((size_t)D_FF * D_MODEL * 2);
  ushort_t* h   = (ushort_t*)alloc((size_t)NTOK * D_MODEL * 2);
  ushort_t* qb  = (ushort_t*)alloc((size_t)NTOK * D_MODEL * 2);
  ushort_t* kb  = (ushort_t*)alloc((size_t)NTOK * D_MODEL * 2);
  ushort_t* vb  = (ushort_t*)alloc((size_t)NTOK * D_MODEL * 2);   // later reused as attn out
  ushort_t* vtb = (ushort_t*)alloc((size_t)NTOK * D_MODEL * 2);
  float*    y   = (float*)   alloc((size_t)NTOK * D_MODEL * 4);
  ushort_t* ub  = (ushort_t*)alloc((size_t)NTOK * D_FF * 2);      // silu(u)*g
  float*    part = (float*)  alloc((size_t)4 * NTOK * D_MODEL * 4);
  const bool use_split = ((size_t)(p - (char*)d_ws) <= ws_size);

  // ---- weight converts: one launch; W1/W3 interleave into w13 ----
  const int nb_dd = D_MODEL * D_MODEL / 4 / 256;   // 1024
  const int nb_fd = D_FF * D_MODEL / 4 / 256;      // 2816
  CvtArgs ca;
  ca.src[0]=WQ; ca.dst[0]=wq;  ca.nblk[0]=nb_dd; ca.mul[0]=1; ca.ofs[0]=0;
  ca.src[1]=WK; ca.dst[1]=wk;  ca.nblk[1]=nb_dd; ca.mul[1]=1; ca.ofs[1]=0;
  ca.src[2]=WV; ca.dst[2]=wv;  ca.nblk[2]=nb_dd; ca.mul[2]=1; ca.ofs[2]=0;
  ca.src[3]=WO; ca.dst[3]=wo;  ca.nblk[3]=nb_dd; ca.mul[3]=1; ca.ofs[3]=0;
  ca.src[4]=W1; ca.dst[4]=w13; ca.nblk[4]=nb_fd; ca.mul[4]=2; ca.ofs[4]=0;
  ca.src[5]=W3; ca.dst[5]=w13; ca.nblk[5]=nb_fd; ca.mul[5]=2; ca.ofs[5]=1;
  ca.src[6]=W2; ca.dst[6]=w2b; ca.nblk[6]=nb_fd; ca.mul[6]=1; ca.ofs[6]=0;
  convert_all<<<4 * nb_dd + 3 * nb_fd, 256, 0, stream>>>(ca);

  rmsnorm_kernel<<<NTOK, 256, 0, stream>>>(x, g1, h);

  QkvArgs qa{h, wq, wk, wv, qb, kb, vb};
  gemm_qkv<<<dim3(D_MODEL / 128, NTOK / 128, 3), 256, 0, stream>>>(qa);

  vtrans_kernel<<<dim3(SEQ / 64, BATCH * NHEADS), 256, 0, stream>>>(vb, vtb);
  attn_kernel<<<dim3((SEQ / 32) * 32, 1), 256, 0, stream>>>(qb, kb, vtb, vb);

  if (use_split) {
    GemmSplitArgs s1{vb, wo, part, D_MODEL, D_MODEL, D_MODEL / 4};
    gemm128_splitk<<<dim3(D_MODEL / 128, NTOK / 128, 4), 256, 0, stream>>>(s1);
    rmsnorm_reduce4<<<NTOK, 256, 0, stream>>>(part, x, g2, y, h);
  } else {
    GemmArgs a2{vb, wo, nullptr, nullptr, y, nullptr, nullptr, x, NTOK, D_MODEL, D_MODEL};
    gemm128<1><<<dim3(D_MODEL / 128, NTOK / 128, 1), 256, 0, stream>>>(a2);
    rmsnorm_kernel<<<NTOK, 256, 0, stream>>>(y, g2, h);
  }

  gemm_ffn13<<<dim3(2 * D_FF / 128, NTOK / 128), 256, 0, stream>>>(h, w13, ub);

  if (use_split) {
    GemmSplitArgs s2{ub, w2b, part, D_MODEL, D_FF, D_FF / 4};
    gemm128_splitk<<<dim3(D_MODEL / 128, NTOK / 128, 4), 256, 0, stream>>>(s2);
    add_reduce4<<<NTOK * D_MODEL / 4 / 256, 256, 0, stream>>>(part, y, out);
  } else {
    GemmArgs a4{ub, w2b, nullptr, nullptr, out, nullptr, nullptr, y, NTOK, D_MODEL, D_FF};
    gemm128<1><<<dim3(D_MODEL / 128, NTOK / 128, 1), 256, 0, stream>>>(a4);
  }
}